// Round 1
// baseline (295.380 us; speedup 1.0000x reference)
//
#include <hip/hip_runtime.h>

#define NN 768
#define UU 64
#define KK 8
#define INF 136   // 2U+K
#define BB 2
#define SLOPE 0.01f

__device__ __forceinline__ float lrelu(float x) { return x > 0.f ? x : SLOPE * x; }

// ---- workspace layout (bytes) ----
// count : 0        (int)
// D     : 512      (768 f32)
// s1    : 4096     (2*768 f32)
// s2    : 10240    (2*768 f32)     -- zero region = first 16384 bytes
// x1    : 16384    (2*768*64 f32 = 393216 B)
// A     : 409600   (2*768*136 f32 = 835584 B)
// Bv    : 1245184  (835584 B)
// pairs : 2080768  (768*768 int worst case = 2359296 B)  -> total 4440064 B

__global__ void k_init(float* ws) {
    int idx = blockIdx.x * blockDim.x + threadIdx.x;
    if (idx < 4096) ws[idx] = 0.f;   // zeroes count, D, s1, s2 (+padding)
}

// one thread per (i,j): mask test, compact pair list, row degree D[i]
__global__ void k_pairs(const float* __restrict__ rel, int* __restrict__ count,
                        int* __restrict__ pairs, float* __restrict__ D) {
    int idx = blockIdx.x * blockDim.x + threadIdx.x;
    if (idx >= NN * NN) return;
    const float* rp = rel + (size_t)idx * KK;
    float sum = 0.f;
#pragma unroll
    for (int k = 0; k < KK; k++) sum += rp[k];
    if (sum > 0.f) {
        int i = idx / NN;
        int j = idx - i * NN;
        int pos = atomicAdd(count, 1);
        pairs[pos] = (i << 16) | j;
        atomicAdd(&D[i], 1.0f);
    }
}

// per (b,i): A[b,i,m] = sum_u x[b,i,u]*W1[u,m]; Bv[b,i,m] = sum_u x[b,i,u]*W1[64+u,m]
__global__ void k_precompute(const float* __restrict__ x, const float* __restrict__ W1,
                             float* __restrict__ A, float* __restrict__ Bv) {
    __shared__ float xs[UU];
    int bi = blockIdx.x;                 // [0, B*N)
    const float* xp = x + (size_t)bi * UU;
    if (threadIdx.x < UU) xs[threadIdx.x] = xp[threadIdx.x];
    __syncthreads();
    for (int m = threadIdx.x; m < INF; m += blockDim.x) {
        float a = 0.f, bv = 0.f;
#pragma unroll 8
        for (int u = 0; u < UU; u++) {
            float xv = xs[u];
            a  += xv * W1[u * INF + m];
            bv += xv * W1[(UU + u) * INF + m];
        }
        A [(size_t)bi * INF + m] = a;
        Bv[(size_t)bi * INF + m] = bv;
    }
}

// one wave per active pair (both batches): R-term + leaky MLP + dot + atomic into s
__global__ void k_hop(const int* __restrict__ count, const int* __restrict__ pairs,
                      const float* __restrict__ A, const float* __restrict__ Bv,
                      const float* __restrict__ rel, const float* __restrict__ W1,
                      const float* __restrict__ b1, const float* __restrict__ w2,
                      const float* __restrict__ b2, const float* __restrict__ D,
                      float* __restrict__ s) {
    int lane = threadIdx.x & 63;
    int wave = (blockIdx.x * blockDim.x + threadIdx.x) >> 6;
    int nwaves = (gridDim.x * blockDim.x) >> 6;
    int cnt = *count;

    float b1v0 = b1[lane];
    float b1v1 = b1[64 + lane];
    float b1v2 = (lane < 8) ? b1[128 + lane] : 0.f;
    float w2v0 = w2[lane];
    float w2v1 = w2[64 + lane];
    float w2v2 = (lane < 8) ? w2[128 + lane] : 0.f;
    float b2v = b2[0];

    for (int p = wave; p < cnt; p += nwaves) {
        int pk = pairs[p];
        int i = pk >> 16, j = pk & 0xffff;

        float r0 = b1v0, r1 = b1v1, r2 = b1v2;
        const float* relp = rel + (size_t)(i * NN + j) * KK;
#pragma unroll
        for (int k = 0; k < KK; k++) {
            float rv = relp[k];
            const float* wrow = W1 + (128 + k) * INF;
            r0 += rv * wrow[lane];
            r1 += rv * wrow[64 + lane];
            if (lane < 8) r2 += rv * wrow[128 + lane];
        }
        float dinv = 1.0f / D[i];

#pragma unroll
        for (int b = 0; b < BB; b++) {
            const float* Ai = A  + ((size_t)b * NN + i) * INF;
            const float* Bj = Bv + ((size_t)b * NN + j) * INF;
            float h0 = lrelu(r0 + Ai[lane]       + Bj[lane]);
            float h1 = lrelu(r1 + Ai[64 + lane]  + Bj[64 + lane]);
            float dot = h0 * w2v0 + h1 * w2v1;
            if (lane < 8) {
                float h2 = lrelu(r2 + Ai[128 + lane] + Bj[128 + lane]);
                dot += h2 * w2v2;
            }
#pragma unroll
            for (int off = 32; off; off >>= 1) dot += __shfl_xor(dot, off, 64);
            if (lane == 0) {
                float o = lrelu(dot + b2v);
                atomicAdd(&s[b * NN + j], o * dinv);
            }
        }
    }
}

// x_out[b,j,u] = x_in[b,j,u] * s[b,j]
__global__ void k_scale(const float* __restrict__ xin, const float* __restrict__ s,
                        float* __restrict__ xout) {
    int idx = blockIdx.x * blockDim.x + threadIdx.x;
    if (idx >= BB * NN * UU) return;
    int bj = idx >> 6;
    xout[idx] = xin[idx] * s[bj];
}

extern "C" void kernel_launch(void* const* d_in, const int* in_sizes, int n_in,
                              void* d_out, int out_size, void* d_ws, size_t ws_size,
                              hipStream_t stream) {
    const float* seq = (const float*)d_in[0];   // (2,768,64)
    const float* rel = (const float*)d_in[1];   // (768,768,8)
    const float* w1_1 = (const float*)d_in[2];  // (136,136)
    const float* b1_1 = (const float*)d_in[3];  // (136,)
    const float* w1_2 = (const float*)d_in[4];  // (136,1)
    const float* b1_2 = (const float*)d_in[5];  // (1,)
    const float* w2_1 = (const float*)d_in[6];
    const float* b2_1 = (const float*)d_in[7];
    const float* w2_2 = (const float*)d_in[8];
    const float* b2_2 = (const float*)d_in[9];
    float* out = (float*)d_out;

    char* ws = (char*)d_ws;
    int*   count = (int*)  (ws + 0);
    float* D     = (float*)(ws + 512);
    float* s1    = (float*)(ws + 4096);
    float* s2    = (float*)(ws + 10240);
    float* x1    = (float*)(ws + 16384);
    float* A     = (float*)(ws + 409600);
    float* Bv    = (float*)(ws + 1245184);
    int*   pairs = (int*)  (ws + 2080768);

    // zero count/D/s1/s2
    k_init<<<16, 256, 0, stream>>>((float*)ws);
    // active pairs + degrees
    k_pairs<<<(NN * NN + 255) / 256, 256, 0, stream>>>(rel, count, pairs, D);

    // ---- hop 1 ----
    k_precompute<<<BB * NN, 128, 0, stream>>>(seq, w1_1, A, Bv);
    k_hop<<<512, 256, 0, stream>>>(count, pairs, A, Bv, rel, w1_1, b1_1, w1_2, b1_2, D, s1);
    k_scale<<<(BB * NN * UU + 255) / 256, 256, 0, stream>>>(seq, s1, x1);

    // ---- hop 2 ----
    k_precompute<<<BB * NN, 128, 0, stream>>>(x1, w2_1, A, Bv);
    k_hop<<<512, 256, 0, stream>>>(count, pairs, A, Bv, rel, w2_1, b2_1, w2_2, b2_2, D, s2);
    k_scale<<<(BB * NN * UU + 255) / 256, 256, 0, stream>>>(x1, s2, out);
}